// Round 5
// baseline (184.742 us; speedup 1.0000x reference)
//
#include <hip/hip_runtime.h>
#include <hip/hip_bf16.h>
#include <stdint.h>

// OuterProductMean: B=1, S=512, R=256, C_M=256, C_P=32, C_Z=128
#define S_DIM 512
#define R_DIM 256
#define CM 256
#define CP 32
#define CZ 128

typedef __attribute__((ext_vector_type(8))) short bf16x8;
typedef __attribute__((ext_vector_type(4))) float f32x4;
typedef unsigned int u32;

__device__ __forceinline__ float bf2f(unsigned short u) {
  union { u32 i; float f; } v; v.i = ((u32)u) << 16; return v.f;
}
__device__ __forceinline__ unsigned short f2bf(float f) {
  union { float f; u32 i; } v; v.f = f;
  u32 x = v.i;
  u32 r = (x + 0x7FFFu + ((x >> 16) & 1u)) >> 16;
  return (unsigned short)r;
}

__device__ __forceinline__ void gload_lds16(const unsigned short* g, unsigned short* l) {
  __builtin_amdgcn_global_load_lds((const __attribute__((address_space(1))) u32*)(g),
                                   (__attribute__((address_space(3))) u32*)(l), 16, 0, 0);
}

__device__ __forceinline__ void wave_bar() {
  asm volatile("" ::: "memory");
  __builtin_amdgcn_s_barrier();
  asm volatile("" ::: "memory");
}

// ---------------- K0 fused: prep W' / permute-cast Wo / mask-norm scale ----------------
// grid 832 x 256: blocks 0..63 prep, 64..575 cast, 576..831 scale
__global__ __launch_bounds__(256) void
fused_prep_kernel(const float* __restrict__ Wa, const float* __restrict__ ba,
                  const float* __restrict__ Wb, const float* __restrict__ bb,
                  const float* __restrict__ ln_g, const float* __restrict__ ln_b,
                  const float* __restrict__ Wo, const float* __restrict__ mask,
                  unsigned short* __restrict__ wp, float* __restrict__ Ka,
                  float* __restrict__ Ca, unsigned short* __restrict__ Wo_bf,
                  float* __restrict__ scale) {
  const int b = blockIdx.x;
  const int t = threadIdx.x;
  if (b < 64) {
    __shared__ float ska[4], sca[4];
    const int o = b;
    const float* W = (o < 32) ? (Wa + o * CM) : (Wb + (o - 32) * CM);
    float wv = W[t];
    unsigned short bv = f2bf(wv * ln_g[t]);
    wp[o * CM + t] = bv;
    float ka = bf2f(bv);
    float ca = wv * ln_b[t];
    #pragma unroll
    for (int m = 1; m < 64; m <<= 1) {
      ka += __shfl_xor(ka, m);
      ca += __shfl_xor(ca, m);
    }
    if ((t & 63) == 0) { ska[t >> 6] = ka; sca[t >> 6] = ca; }
    __syncthreads();
    if (t == 0) {
      Ka[o] = ska[0] + ska[1] + ska[2] + ska[3];
      Ca[o] = sca[0] + sca[1] + sca[2] + sca[3] + ((o < 32) ? ba[o] : bb[o - 32]);
    }
  } else if (b < 576) {
    // Wo cast + transpose to k' = e*32+d (matches epilogue O layout)
    int idx = (b - 64) * 256 + t;
    int z = idx >> 10, k = idx & 1023;
    int d = k >> 5, e = k & 31;
    Wo_bf[(z << 10) + e * 32 + d] = f2bf(Wo[idx]);
  } else {
    const int i = b - 576, j = t;
    float sum = 0.f;
    for (int s = 0; s < S_DIM; ++s)
      sum += mask[s * R_DIM + i] * mask[s * R_DIM + j];
    scale[i * R_DIM + j] = 1.0f / (1e-3f + sum);
  }
}

// ---------------- K1: fused LN + projections -> leftT/rightT bf16 [8192][512] ----------------
#define K1_ROWS 64
#define XPAD 264

__global__ __launch_bounds__(256) void
ln_proj_kernel(const float* __restrict__ M, const float* __restrict__ mask,
               const unsigned short* __restrict__ wp_g, const float* __restrict__ Ka_g,
               const float* __restrict__ Ca_g,
               unsigned short* __restrict__ leftT, unsigned short* __restrict__ rightT) {
  __shared__ unsigned short xt[K1_ROWS * XPAD];
  __shared__ unsigned short wp[64 * XPAD];
  __shared__ float smu[K1_ROWS], srs[K1_ROWS], smk[K1_ROWS];
  __shared__ float sKa[64], sCa[64];

  const int t = threadIdx.x;
  const int lane = t & 63;
  const int w = t >> 6;
  const int lm = lane & 15;
  const int rr = lane >> 4;
  const int i = blockIdx.x;
  const int s0 = blockIdx.y * K1_ROWS;

  for (int idx = t; idx < 64 * CM / 8; idx += 256) {
    int row = idx >> 5;
    int col = (idx & 31) * 8;
    *(uint4*)(&wp[row * XPAD + col]) = *(const uint4*)(wp_g + row * CM + col);
  }
  if (t < 64) { sKa[t] = Ka_g[t]; sCa[t] = Ca_g[t]; }

  #pragma unroll
  for (int it = 0; it < 4; ++it) {
    const int row = w * 16 + it * 4 + rr;
    const int sg = s0 + row;
    const float* src = M + ((size_t)sg * R_DIM + i) * CM;
    float4 x[4];
    #pragma unroll
    for (int ch = 0; ch < 4; ++ch) x[ch] = *(const float4*)(src + ch * 64 + lm * 4);
    float sum = 0.f, ssq = 0.f;
    #pragma unroll
    for (int ch = 0; ch < 4; ++ch) {
      sum += x[ch].x + x[ch].y + x[ch].z + x[ch].w;
      ssq += x[ch].x * x[ch].x + x[ch].y * x[ch].y + x[ch].z * x[ch].z + x[ch].w * x[ch].w;
    }
    #pragma unroll
    for (int m = 1; m < 16; m <<= 1) {
      sum += __shfl_xor(sum, m);
      ssq += __shfl_xor(ssq, m);
    }
    float mu = sum * (1.0f / CM);
    float var = ssq * (1.0f / CM) - mu * mu;
    float rs = rsqrtf(var + 1e-5f);
    if (lm == 0) {
      smu[row] = mu; srs[row] = rs;
      smk[row] = mask[(size_t)sg * R_DIM + i];
    }
    #pragma unroll
    for (int ch = 0; ch < 4; ++ch) {
      ushort4 xb;
      xb.x = f2bf(x[ch].x); xb.y = f2bf(x[ch].y); xb.z = f2bf(x[ch].z); xb.w = f2bf(x[ch].w);
      *(ushort4*)(&xt[row * XPAD + ch * 64 + lm * 4]) = xb;
    }
  }
  __syncthreads();

  f32x4 acc[4] = {{0.f, 0.f, 0.f, 0.f}, {0.f, 0.f, 0.f, 0.f},
                  {0.f, 0.f, 0.f, 0.f}, {0.f, 0.f, 0.f, 0.f}};
  #pragma unroll
  for (int k = 0; k < 8; ++k) {
    const int c0 = k * 32 + ((lane >> 4) << 3);
    bf16x8 a = *(const bf16x8*)(&wp[(w * 16 + (lane & 15)) * XPAD + c0]);
    #pragma unroll
    for (int nt = 0; nt < 4; ++nt) {
      bf16x8 b = *(const bf16x8*)(&xt[(nt * 16 + (lane & 15)) * XPAD + c0]);
      acc[nt] = __builtin_amdgcn_mfma_f32_16x16x32_bf16(a, b, acc[nt], 0, 0, 0);
    }
  }

  #pragma unroll
  for (int nt = 0; nt < 4; ++nt) {
    int srow = nt * 16 + (lane & 15);
    float mu = smu[srow], rs = srs[srow], mk = smk[srow];
    int sg = s0 + srow;
    #pragma unroll
    for (int r = 0; r < 4; ++r) {
      int o = w * 16 + ((lane >> 4) << 2) + r;
      float v = (rs * (acc[nt][r] - mu * sKa[o]) + sCa[o]) * mk;
      unsigned short bv = f2bf(v);
      if (o < 32) leftT[(size_t)(i * 32 + o) * S_DIM + sg] = bv;
      else        rightT[(size_t)(i * 32 + (o - 32)) * S_DIM + sg] = bv;
    }
  }
}

// ---------------- K2: 256x256 tile, 16 waves (64x64/wave), BK=64 dbuf + fused Wo ----------------
#define NT2 8   // 512 / 64 K-tiles

__global__ __launch_bounds__(1024) void
opm_gemm_kernel(const unsigned short* __restrict__ leftT, const unsigned short* __restrict__ rightT,
                const unsigned short* __restrict__ Wo_bf, const float* __restrict__ bo,
                const float* __restrict__ scale, float* __restrict__ out) {
  extern __shared__ unsigned short smem[];  // 65536 shorts = 128 KiB

  const int t = threadIdx.x;
  const int lane = t & 63;
  const int lm = lane & 15, lq = lane >> 4;
  const int sw = lm & 7;
  const int w = t >> 6;            // 0..15
  const int wmm = w >> 2, wnn = w & 3;

  // XCD chunk = 128 blocks; within chunk bx-major: A panels L2-resident
  const int bid = blockIdx.x;
  const int xcd = bid & 7, local = bid >> 3;
  const int by = xcd * 4 + (local & 3);
  const int bx = local >> 2;

  const unsigned short* Asrc = leftT + (size_t)(by * 256) * S_DIM;
  const unsigned short* Bsrc = rightT + (size_t)(bx * 256) * S_DIM;

  // staging: chunk c = q*1024+t -> LDS row c>>3, slot c&7; global slot (c&7)^((c>>3)&7)
  int sr[2], so[2];
  #pragma unroll
  for (int q = 0; q < 2; ++q) {
    int c = q * 1024 + t;
    sr[q] = c >> 3;
    so[q] = ((c & 7) ^ ((c >> 3) & 7)) * 8;
  }

  f32x4 acc[4][4];
  #pragma unroll
  for (int a = 0; a < 4; ++a)
    #pragma unroll
    for (int b = 0; b < 4; ++b) acc[a][b] = (f32x4){0.f, 0.f, 0.f, 0.f};

  // STAGE(tile kt -> buffer buf): 4 gloads/thread (2 A + 2 B)
  auto STAGE = [&](int kt, int buf) {
    const int kb = kt * 64;
    unsigned short* ab = smem + buf * 32768;
    #pragma unroll
    for (int q = 0; q < 2; ++q) {
      int c = q * 1024 + t;
      gload_lds16(Asrc + (size_t)sr[q] * S_DIM + kb + so[q], ab + c * 8);
      gload_lds16(Bsrc + (size_t)sr[q] * S_DIM + kb + so[q], ab + 16384 + c * 8);
    }
  };

  STAGE(0, 0);
  STAGE(1, 1);

  #pragma unroll
  for (int kt = 0; kt < NT2; ++kt) {
    const int cur = kt & 1;
    if (kt < NT2 - 1) asm volatile("s_waitcnt vmcnt(4)" ::: "memory");
    else              asm volatile("s_waitcnt vmcnt(0)" ::: "memory");
    wave_bar();

    const unsigned short* Ab = smem + cur * 32768;
    const unsigned short* Bb = Ab + 16384;
    #pragma unroll
    for (int ks = 0; ks < 2; ++ks) {
      const int kp = ks * 4 + lq;
      const int slot = (kp ^ sw) << 3;
      bf16x8 af[4], bfr[4];
      #pragma unroll
      for (int mi = 0; mi < 4; ++mi)
        af[mi] = *(const bf16x8*)(&Ab[(wmm * 64 + mi * 16 + lm) * 64 + slot]);
      #pragma unroll
      for (int ni = 0; ni < 4; ++ni)
        bfr[ni] = *(const bf16x8*)(&Bb[(wnn * 64 + ni * 16 + lm) * 64 + slot]);
      __builtin_amdgcn_s_setprio(1);
      #pragma unroll
      for (int mi = 0; mi < 4; ++mi)
        #pragma unroll
        for (int ni = 0; ni < 4; ++ni)
          acc[mi][ni] = __builtin_amdgcn_mfma_f32_16x16x32_bf16(af[mi], bfr[ni], acc[mi][ni], 0, 0, 0);
      __builtin_amdgcn_s_setprio(0);
    }

    wave_bar();
    if (kt + 2 < NT2) STAGE(kt + 2, cur);
  }

  // ---- epilogue part 1: acc -> Ob[pair][k'=e*32+d], b64 writes, dual-XOR swizzle ----
  #pragma unroll
  for (int mi = 0; mi < 4; ++mi) {
    const int m0 = wmm * 64 + mi * 16 + lq * 4;
    const int il = m0 >> 5, d0 = m0 & 31;
    #pragma unroll
    for (int ni = 0; ni < 4; ++ni) {
      const int n = wnn * 64 + ni * 16 + lm;
      const int jl = n >> 5, e = n & 31;
      const int pair = il * 8 + jl;
      u32 off = ((u32)(64 * e + 2 * d0)) ^ ((u32)(e & 7) << 4) ^ ((u32)(pair & 7) << 4);
      ushort4 v4;
      v4.x = f2bf(acc[mi][ni][0]); v4.y = f2bf(acc[mi][ni][1]);
      v4.z = f2bf(acc[mi][ni][2]); v4.w = f2bf(acc[mi][ni][3]);
      *(ushort4*)((char*)smem + (u32)pair * 2048 + off) = v4;
    }
  }
  __syncthreads();

  // ---- epilogue part 2: Z[pair][z] = O[pair][:] . Wo_perm[z][:]  (M=64, K=1024, N=128) ----
  const int wz = w & 7, wph = w >> 3;
  f32x4 zacc[2] = {{0.f, 0.f, 0.f, 0.f}, {0.f, 0.f, 0.f, 0.f}};
  const unsigned short* wsrc = Wo_bf + (size_t)(wz * 16 + lm) * (CP * CP) + lq * 8;
  #pragma unroll 8
  for (int kk = 0; kk < 32; ++kk) {
    bf16x8 bw = *(const bf16x8*)(wsrc + kk * 32);
    #pragma unroll
    for (int pt = 0; pt < 2; ++pt) {
      const int pairL = wph * 32 + pt * 16 + lm;
      u32 off = ((u32)(kk * 64 + lq * 16)) ^ ((u32)(kk & 7) << 4) ^ ((u32)(pairL & 7) << 4);
      bf16x8 a = *(const bf16x8*)((const char*)smem + (u32)pairL * 2048 + off);
      zacc[pt] = __builtin_amdgcn_mfma_f32_16x16x32_bf16(a, bw, zacc[pt], 0, 0, 0);
    }
  }

  const int z = wz * 16 + lm;
  const float bz = bo[z];
  #pragma unroll
  for (int pt = 0; pt < 2; ++pt) {
    #pragma unroll
    for (int r = 0; r < 4; ++r) {
      const int pair = wph * 32 + pt * 16 + lq * 4 + r;
      const int ig = by * 8 + (pair >> 3), jg = bx * 8 + (pair & 7);
      float v = (zacc[pt][r] + bz) * scale[ig * R_DIM + jg];
      out[((size_t)ig * R_DIM + jg) * CZ + z] = v;
    }
  }
}

extern "C" void kernel_launch(void* const* d_in, const int* in_sizes, int n_in,
                              void* d_out, int out_size, void* d_ws, size_t ws_size,
                              hipStream_t stream) {
  const float* M     = (const float*)d_in[0];
  const float* Mmask = (const float*)d_in[1];
  const float* ln_g  = (const float*)d_in[3];
  const float* ln_b  = (const float*)d_in[4];
  const float* Wa    = (const float*)d_in[5];
  const float* ba    = (const float*)d_in[6];
  const float* Wb    = (const float*)d_in[7];
  const float* bb    = (const float*)d_in[8];
  const float* Wo    = (const float*)d_in[9];
  const float* bo    = (const float*)d_in[10];
  float* out = (float*)d_out;

  char* ws = (char*)d_ws;
  unsigned short* leftT  = (unsigned short*)(ws);
  unsigned short* rightT = (unsigned short*)(ws + 8388608);
  unsigned short* wp     = (unsigned short*)(ws + 16777216);
  float*          Ka     = (float*)(ws + 16810240);
  float*          Ca     = (float*)(ws + 16810496);
  unsigned short* Wo_bf  = (unsigned short*)(ws + 16810752);
  float*          scale  = (float*)(ws + 17072896);
  (void)ws_size; (void)in_sizes; (void)n_in; (void)out_size;

  hipFuncSetAttribute((const void*)opm_gemm_kernel,
                      hipFuncAttributeMaxDynamicSharedMemorySize, 131072);

  hipLaunchKernelGGL(fused_prep_kernel, dim3(832), dim3(256), 0, stream,
                     Wa, ba, Wb, bb, ln_g, ln_b, Wo, Mmask, wp, Ka, Ca, Wo_bf, scale);
  hipLaunchKernelGGL(ln_proj_kernel, dim3(R_DIM, S_DIM / K1_ROWS), dim3(256), 0, stream,
                     M, Mmask, wp, Ka, Ca, leftT, rightT);
  hipLaunchKernelGGL(opm_gemm_kernel, dim3(1024), dim3(1024), 131072, stream,
                     leftT, rightT, Wo_bf, bo, scale, out);
}

// Round 6
// 162.298 us; speedup vs baseline: 1.1383x; 1.1383x over previous
//
#include <hip/hip_runtime.h>
#include <hip/hip_bf16.h>
#include <stdint.h>

// OuterProductMean: B=1, S=512, R=256, C_M=256, C_P=32, C_Z=128
#define S_DIM 512
#define R_DIM 256
#define CM 256
#define CP 32
#define CZ 128

typedef __attribute__((ext_vector_type(8))) short bf16x8;
typedef __attribute__((ext_vector_type(4))) float f32x4;
typedef unsigned int u32;

__device__ __forceinline__ float bf2f(unsigned short u) {
  union { u32 i; float f; } v; v.i = ((u32)u) << 16; return v.f;
}
__device__ __forceinline__ unsigned short f2bf(float f) {
  union { float f; u32 i; } v; v.f = f;
  u32 x = v.i;
  u32 r = (x + 0x7FFFu + ((x >> 16) & 1u)) >> 16;
  return (unsigned short)r;
}

__device__ __forceinline__ void gload_lds16(const unsigned short* g, unsigned short* l) {
  __builtin_amdgcn_global_load_lds((const __attribute__((address_space(1))) u32*)(g),
                                   (__attribute__((address_space(3))) u32*)(l), 16, 0, 0);
}

// ---------------- K0 fused: prep W' / permute-cast Wo / mask-norm scale ----------------
__global__ __launch_bounds__(256) void
fused_prep_kernel(const float* __restrict__ Wa, const float* __restrict__ ba,
                  const float* __restrict__ Wb, const float* __restrict__ bb,
                  const float* __restrict__ ln_g, const float* __restrict__ ln_b,
                  const float* __restrict__ Wo, const float* __restrict__ mask,
                  unsigned short* __restrict__ wp, float* __restrict__ Ka,
                  float* __restrict__ Ca, unsigned short* __restrict__ Wo_bf,
                  float* __restrict__ scale) {
  const int b = blockIdx.x;
  const int t = threadIdx.x;
  if (b < 64) {
    __shared__ float ska[4], sca[4];
    const int o = b;
    const float* W = (o < 32) ? (Wa + o * CM) : (Wb + (o - 32) * CM);
    float wv = W[t];
    unsigned short bv = f2bf(wv * ln_g[t]);
    wp[o * CM + t] = bv;
    float ka = bf2f(bv);
    float ca = wv * ln_b[t];
    #pragma unroll
    for (int m = 1; m < 64; m <<= 1) {
      ka += __shfl_xor(ka, m);
      ca += __shfl_xor(ca, m);
    }
    if ((t & 63) == 0) { ska[t >> 6] = ka; sca[t >> 6] = ca; }
    __syncthreads();
    if (t == 0) {
      Ka[o] = ska[0] + ska[1] + ska[2] + ska[3];
      Ca[o] = sca[0] + sca[1] + sca[2] + sca[3] + ((o < 32) ? ba[o] : bb[o - 32]);
    }
  } else if (b < 576) {
    // Wo cast + transpose to k' = e*32+d (matches epilogue O layout)
    int idx = (b - 64) * 256 + t;
    int z = idx >> 10, k = idx & 1023;
    int d = k >> 5, e = k & 31;
    Wo_bf[(z << 10) + e * 32 + d] = f2bf(Wo[idx]);
  } else {
    const int i = b - 576, j = t;
    float sum = 0.f;
    for (int s = 0; s < S_DIM; ++s)
      sum += mask[s * R_DIM + i] * mask[s * R_DIM + j];
    scale[i * R_DIM + j] = 1.0f / (1e-3f + sum);
  }
}

// ---------------- K1: fused LN + projections -> leftT/rightT bf16 [8192][512] ----------------
#define K1_ROWS 64
#define XPAD 264

__global__ __launch_bounds__(256) void
ln_proj_kernel(const float* __restrict__ M, const float* __restrict__ mask,
               const unsigned short* __restrict__ wp_g, const float* __restrict__ Ka_g,
               const float* __restrict__ Ca_g,
               unsigned short* __restrict__ leftT, unsigned short* __restrict__ rightT) {
  __shared__ unsigned short xt[K1_ROWS * XPAD];
  __shared__ unsigned short wp[64 * XPAD];
  __shared__ float smu[K1_ROWS], srs[K1_ROWS], smk[K1_ROWS];
  __shared__ float sKa[64], sCa[64];

  const int t = threadIdx.x;
  const int lane = t & 63;
  const int w = t >> 6;
  const int lm = lane & 15;
  const int rr = lane >> 4;
  const int i = blockIdx.x;
  const int s0 = blockIdx.y * K1_ROWS;

  for (int idx = t; idx < 64 * CM / 8; idx += 256) {
    int row = idx >> 5;
    int col = (idx & 31) * 8;
    *(uint4*)(&wp[row * XPAD + col]) = *(const uint4*)(wp_g + row * CM + col);
  }
  if (t < 64) { sKa[t] = Ka_g[t]; sCa[t] = Ca_g[t]; }

  #pragma unroll
  for (int it = 0; it < 4; ++it) {
    const int row = w * 16 + it * 4 + rr;
    const int sg = s0 + row;
    const float* src = M + ((size_t)sg * R_DIM + i) * CM;
    float4 x[4];
    #pragma unroll
    for (int ch = 0; ch < 4; ++ch) x[ch] = *(const float4*)(src + ch * 64 + lm * 4);
    float sum = 0.f, ssq = 0.f;
    #pragma unroll
    for (int ch = 0; ch < 4; ++ch) {
      sum += x[ch].x + x[ch].y + x[ch].z + x[ch].w;
      ssq += x[ch].x * x[ch].x + x[ch].y * x[ch].y + x[ch].z * x[ch].z + x[ch].w * x[ch].w;
    }
    #pragma unroll
    for (int m = 1; m < 16; m <<= 1) {
      sum += __shfl_xor(sum, m);
      ssq += __shfl_xor(ssq, m);
    }
    float mu = sum * (1.0f / CM);
    float var = ssq * (1.0f / CM) - mu * mu;
    float rs = rsqrtf(var + 1e-5f);
    if (lm == 0) {
      smu[row] = mu; srs[row] = rs;
      smk[row] = mask[(size_t)sg * R_DIM + i];
    }
    #pragma unroll
    for (int ch = 0; ch < 4; ++ch) {
      ushort4 xb;
      xb.x = f2bf(x[ch].x); xb.y = f2bf(x[ch].y); xb.z = f2bf(x[ch].z); xb.w = f2bf(x[ch].w);
      *(ushort4*)(&xt[row * XPAD + ch * 64 + lm * 4]) = xb;
    }
  }
  __syncthreads();

  f32x4 acc[4] = {{0.f, 0.f, 0.f, 0.f}, {0.f, 0.f, 0.f, 0.f},
                  {0.f, 0.f, 0.f, 0.f}, {0.f, 0.f, 0.f, 0.f}};
  #pragma unroll
  for (int k = 0; k < 8; ++k) {
    const int c0 = k * 32 + ((lane >> 4) << 3);
    bf16x8 a = *(const bf16x8*)(&wp[(w * 16 + (lane & 15)) * XPAD + c0]);
    #pragma unroll
    for (int nt = 0; nt < 4; ++nt) {
      bf16x8 b = *(const bf16x8*)(&xt[(nt * 16 + (lane & 15)) * XPAD + c0]);
      acc[nt] = __builtin_amdgcn_mfma_f32_16x16x32_bf16(a, b, acc[nt], 0, 0, 0);
    }
  }

  #pragma unroll
  for (int nt = 0; nt < 4; ++nt) {
    int srow = nt * 16 + (lane & 15);
    float mu = smu[srow], rs = srs[srow], mk = smk[srow];
    int sg = s0 + srow;
    #pragma unroll
    for (int r = 0; r < 4; ++r) {
      int o = w * 16 + ((lane >> 4) << 2) + r;
      float v = (rs * (acc[nt][r] - mu * sKa[o]) + sCa[o]) * mk;
      unsigned short bv = f2bf(v);
      if (o < 32) leftT[(size_t)(i * 32 + o) * S_DIM + sg] = bv;
      else        rightT[(size_t)(i * 32 + (o - 32)) * S_DIM + sg] = bv;
    }
  }
}

// ---------------- K2: 256x256 tile, 8 waves (128x64/wave), 4-phase K-slice pipeline ----------------
// K-slices of 32 (A+B = 32KB) in a 3-slot LDS ring (96KB). Per phase:
// {stage ∥ ds_read -> barrier -> lgkm(0) -> setprio(1) -> 16 MFMA -> setprio(0) -> barrier}.
// Counted vmcnt(4) only at P1/P3 ends. Epilogue: transposed-k' O in LDS + fused Wo MFMA.
#define NT2 8   // 512 / 64 K-tiles; 16 slices of 32

__global__ __launch_bounds__(512, 1) void
opm_gemm_kernel(const unsigned short* __restrict__ leftT, const unsigned short* __restrict__ rightT,
                const unsigned short* __restrict__ Wo_bf, const float* __restrict__ bo,
                const float* __restrict__ scale, float* __restrict__ out) {
  extern __shared__ unsigned short smem[];  // 65536 shorts = 128 KiB (ring uses 96 KiB)

  const int t = threadIdx.x;
  const int lane = t & 63;
  const int lm = lane & 15, lq = lane >> 4;
  const int w = t >> 6;            // 0..7
  const int wm = w >> 2, wn = w & 3;

  // XCD chunk = 128 blocks; within chunk bx-major: A panels L2-resident
  const int bid = blockIdx.x;
  const int xcd = bid & 7, local = bid >> 3;
  const int by = xcd * 4 + (local & 3);
  const int bx = local >> 2;

  const unsigned short* Asrc = leftT + (size_t)(by * 256) * S_DIM;
  const unsigned short* Bsrc = rightT + (size_t)(bx * 256) * S_DIM;

  // staging decode: chunks c = t, t+512 per matrix; row = c>>2 (64B rows), lds slot c&3,
  // global slot = (c&3) ^ ((row>>1)&3)  [source-side swizzle; linear LDS dest]
  int srow[2], ssrc[2], sdst[2];
  #pragma unroll
  for (int q = 0; q < 2; ++q) {
    int c = q * 512 + t;
    int row = c >> 2, sl = c & 3;
    srow[q] = row;
    ssrc[q] = (sl ^ ((row >> 1) & 3)) * 8;
    sdst[q] = row * 32 + sl * 8;
  }

  f32x4 acc[8][4];
  #pragma unroll
  for (int a = 0; a < 8; ++a)
    #pragma unroll
    for (int b = 0; b < 4; ++b) acc[a][b] = (f32x4){0.f, 0.f, 0.f, 0.f};

  // STAGE slice s (32 k) into ring slot s%3: 4 gloads/thread (2 A + 2 B)
  auto STAGE = [&](int s) {
    unsigned short* base = smem + (s % 3) * 16384;
    const int kb = s * 32;
    #pragma unroll
    for (int q = 0; q < 2; ++q) {
      gload_lds16(Asrc + (size_t)srow[q] * S_DIM + kb + ssrc[q], base + sdst[q]);
      gload_lds16(Bsrc + (size_t)srow[q] * S_DIM + kb + ssrc[q], base + 8192 + sdst[q]);
    }
  };

  // read-side swizzled k-slot (same involution as source permute)
  const int sl8 = (lq ^ ((lm >> 1) & 3)) * 8;

  bf16x8 afl[4], afh[4], bfr[4];

  STAGE(0); STAGE(1);
  asm volatile("s_waitcnt vmcnt(4)" ::: "memory");   // slice 0 landed
  __builtin_amdgcn_s_barrier();

  #pragma unroll
  for (int kt = 0; kt < NT2; ++kt) {
    const unsigned short* A0 = smem + ((2 * kt) % 3) * 16384;
    const unsigned short* B0 = A0 + 8192;
    const unsigned short* A1 = smem + ((2 * kt + 1) % 3) * 16384;
    const unsigned short* B1 = A1 + 8192;

    // ---- P0: stage slice 2kt+2; read A-lo + B (ks0); MFMA mi0-3 ----
    if (kt + 1 < NT2) STAGE(2 * kt + 2);
    #pragma unroll
    for (int mi = 0; mi < 4; ++mi)
      afl[mi] = *(const bf16x8*)(&A0[(wm * 128 + mi * 16 + lm) * 32 + sl8]);
    #pragma unroll
    for (int ni = 0; ni < 4; ++ni)
      bfr[ni] = *(const bf16x8*)(&B0[(wn * 64 + ni * 16 + lm) * 32 + sl8]);
    __builtin_amdgcn_s_barrier();
    asm volatile("s_waitcnt lgkmcnt(0)" ::: "memory");
    __builtin_amdgcn_sched_barrier(0);
    __builtin_amdgcn_s_setprio(1);
    #pragma unroll
    for (int mi = 0; mi < 4; ++mi)
      #pragma unroll
      for (int ni = 0; ni < 4; ++ni)
        acc[mi][ni] = __builtin_amdgcn_mfma_f32_16x16x32_bf16(afl[mi], bfr[ni], acc[mi][ni], 0, 0, 0);
    __builtin_amdgcn_s_setprio(0);
    __builtin_amdgcn_s_barrier();

    // ---- P1: read A-hi (ks0); MFMA mi4-7; vmcnt for slice 2kt+1 ----
    #pragma unroll
    for (int mi = 0; mi < 4; ++mi)
      afh[mi] = *(const bf16x8*)(&A0[(wm * 128 + (4 + mi) * 16 + lm) * 32 + sl8]);
    __builtin_amdgcn_s_barrier();
    asm volatile("s_waitcnt lgkmcnt(0)" ::: "memory");
    __builtin_amdgcn_sched_barrier(0);
    __builtin_amdgcn_s_setprio(1);
    #pragma unroll
    for (int mi = 0; mi < 4; ++mi)
      #pragma unroll
      for (int ni = 0; ni < 4; ++ni)
        acc[4 + mi][ni] = __builtin_amdgcn_mfma_f32_16x16x32_bf16(afh[mi], bfr[ni], acc[4 + mi][ni], 0, 0, 0);
    __builtin_amdgcn_s_setprio(0);
    if (kt == NT2 - 1) asm volatile("s_waitcnt vmcnt(0)" ::: "memory");
    else               asm volatile("s_waitcnt vmcnt(4)" ::: "memory");
    __builtin_amdgcn_s_barrier();

    // ---- P2: stage slice 2kt+3; read A-lo + B (ks1); MFMA mi0-3 ----
    if (kt + 1 < NT2) STAGE(2 * kt + 3);
    #pragma unroll
    for (int mi = 0; mi < 4; ++mi)
      afl[mi] = *(const bf16x8*)(&A1[(wm * 128 + mi * 16 + lm) * 32 + sl8]);
    #pragma unroll
    for (int ni = 0; ni < 4; ++ni)
      bfr[ni] = *(const bf16x8*)(&B1[(wn * 64 + ni * 16 + lm) * 32 + sl8]);
    __builtin_amdgcn_s_barrier();
    asm volatile("s_waitcnt lgkmcnt(0)" ::: "memory");
    __builtin_amdgcn_sched_barrier(0);
    __builtin_amdgcn_s_setprio(1);
    #pragma unroll
    for (int mi = 0; mi < 4; ++mi)
      #pragma unroll
      for (int ni = 0; ni < 4; ++ni)
        acc[mi][ni] = __builtin_amdgcn_mfma_f32_16x16x32_bf16(afl[mi], bfr[ni], acc[mi][ni], 0, 0, 0);
    __builtin_amdgcn_s_setprio(0);
    __builtin_amdgcn_s_barrier();

    // ---- P3: read A-hi (ks1); MFMA mi4-7; vmcnt for slice 2kt+2 ----
    #pragma unroll
    for (int mi = 0; mi < 4; ++mi)
      afh[mi] = *(const bf16x8*)(&A1[(wm * 128 + (4 + mi) * 16 + lm) * 32 + sl8]);
    __builtin_amdgcn_s_barrier();
    asm volatile("s_waitcnt lgkmcnt(0)" ::: "memory");
    __builtin_amdgcn_sched_barrier(0);
    __builtin_amdgcn_s_setprio(1);
    #pragma unroll
    for (int mi = 0; mi < 4; ++mi)
      #pragma unroll
      for (int ni = 0; ni < 4; ++ni)
        acc[4 + mi][ni] = __builtin_amdgcn_mfma_f32_16x16x32_bf16(afh[mi], bfr[ni], acc[4 + mi][ni], 0, 0, 0);
    __builtin_amdgcn_s_setprio(0);
    if (kt + 1 < NT2) asm volatile("s_waitcnt vmcnt(4)" ::: "memory");
    __builtin_amdgcn_s_barrier();
  }

  // ---- epilogue part 1: acc -> Ob[pair][k'=e*32+d] bf16, b64 writes, dual-XOR ----
  #pragma unroll
  for (int mi = 0; mi < 8; ++mi) {
    const int m0 = wm * 128 + mi * 16 + lq * 4;
    const int il = m0 >> 5, d0 = m0 & 31;
    #pragma unroll
    for (int ni = 0; ni < 4; ++ni) {
      const int n = wn * 64 + ni * 16 + lm;
      const int jl = n >> 5, e = n & 31;
      const int pair = il * 8 + jl;
      u32 off = ((u32)(64 * e + 2 * d0)) ^ ((u32)(e & 7) << 4) ^ ((u32)(pair & 7) << 4);
      ushort4 v4;
      v4.x = f2bf(acc[mi][ni][0]); v4.y = f2bf(acc[mi][ni][1]);
      v4.z = f2bf(acc[mi][ni][2]); v4.w = f2bf(acc[mi][ni][3]);
      *(ushort4*)((char*)smem + (u32)pair * 2048 + off) = v4;
    }
  }
  __syncthreads();

  // ---- epilogue part 2: Z[pair][z] = O[pair][:] . Wo_perm[z][:]  (M=64, K=1024, N=128) ----
  f32x4 zacc[4] = {{0.f, 0.f, 0.f, 0.f}, {0.f, 0.f, 0.f, 0.f},
                   {0.f, 0.f, 0.f, 0.f}, {0.f, 0.f, 0.f, 0.f}};
  const unsigned short* wsrc = Wo_bf + (size_t)(w * 16 + lm) * (CP * CP) + lq * 8;
  #pragma unroll 4
  for (int kk = 0; kk < 32; ++kk) {
    bf16x8 bw = *(const bf16x8*)(wsrc + kk * 32);
    #pragma unroll
    for (int pt = 0; pt < 4; ++pt) {
      const int pairL = pt * 16 + lm;
      u32 off = ((u32)(kk * 64 + lq * 16)) ^ ((u32)(kk & 7) << 4) ^ ((u32)(pairL & 7) << 4);
      bf16x8 a = *(const bf16x8*)((const char*)smem + (u32)pairL * 2048 + off);
      zacc[pt] = __builtin_amdgcn_mfma_f32_16x16x32_bf16(a, bw, zacc[pt], 0, 0, 0);
    }
  }

  const int z = w * 16 + lm;
  const float bz = bo[z];
  #pragma unroll
  for (int pt = 0; pt < 4; ++pt) {
    #pragma unroll
    for (int r = 0; r < 4; ++r) {
      const int pair = pt * 16 + lq * 4 + r;
      const int ig = by * 8 + (pair >> 3), jg = bx * 8 + (pair & 7);
      float v = (zacc[pt][r] + bz) * scale[ig * R_DIM + jg];
      out[((size_t)ig * R_DIM + jg) * CZ + z] = v;
    }
  }
}

extern "C" void kernel_launch(void* const* d_in, const int* in_sizes, int n_in,
                              void* d_out, int out_size, void* d_ws, size_t ws_size,
                              hipStream_t stream) {
  const float* M     = (const float*)d_in[0];
  const float* Mmask = (const float*)d_in[1];
  const float* ln_g  = (const float*)d_in[3];
  const float* ln_b  = (const float*)d_in[4];
  const float* Wa    = (const float*)d_in[5];
  const float* ba    = (const float*)d_in[6];
  const float* Wb    = (const float*)d_in[7];
  const float* bb    = (const float*)d_in[8];
  const float* Wo    = (const float*)d_in[9];
  const float* bo    = (const float*)d_in[10];
  float* out = (float*)d_out;

  char* ws = (char*)d_ws;
  unsigned short* leftT  = (unsigned short*)(ws);
  unsigned short* rightT = (unsigned short*)(ws + 8388608);
  unsigned short* wp     = (unsigned short*)(ws + 16777216);
  float*          Ka     = (float*)(ws + 16810240);
  float*          Ca     = (float*)(ws + 16810496);
  unsigned short* Wo_bf  = (unsigned short*)(ws + 16810752);
  float*          scale  = (float*)(ws + 17072896);
  (void)ws_size; (void)in_sizes; (void)n_in; (void)out_size;

  hipFuncSetAttribute((const void*)opm_gemm_kernel,
                      hipFuncAttributeMaxDynamicSharedMemorySize, 131072);

  hipLaunchKernelGGL(fused_prep_kernel, dim3(832), dim3(256), 0, stream,
                     Wa, ba, Wb, bb, ln_g, ln_b, Wo, Mmask, wp, Ka, Ca, Wo_bf, scale);
  hipLaunchKernelGGL(ln_proj_kernel, dim3(R_DIM, S_DIM / K1_ROWS), dim3(256), 0, stream,
                     M, Mmask, wp, Ka, Ca, leftT, rightT);
  hipLaunchKernelGGL(opm_gemm_kernel, dim3(1024), dim3(512), 131072, stream,
                     leftT, rightT, Wo_bf, bo, scale, out);
}